// Round 9
// baseline (203.552 us; speedup 1.0000x reference)
//
#include <hip/hip_runtime.h>

#define KD 1536
#define ND 3072
#define TT 16

typedef __attribute__((ext_vector_type(8))) short short8;
typedef __attribute__((ext_vector_type(4))) float floatx4;

__device__ __forceinline__ unsigned short f2bf(float f) {
    unsigned int x = __float_as_uint(f);
    unsigned int r = (x + 0x7fffu + ((x >> 16) & 1u)) >> 16;
    return (unsigned short)r;
}

#define MF(a, b, c) __builtin_amdgcn_mfma_f32_16x16x32_bf16(a, b, c, 0, 0, 0)

// =============== prep: packA (0..383, even rows only) / packB (384..767) ===============
__global__ __launch_bounds__(256) void prep_k(const float* __restrict__ y,
                                              const float* __restrict__ conv_w,
                                              unsigned short* __restrict__ Ap,
                                              unsigned short* __restrict__ Bp) {
    __shared__ float smA[64 * 99];   // 7 even rows x 14 cols per channel, pitch 99
    const int bid = blockIdx.x;
    const int tid = threadIdx.x;

    if (bid < 384) {
        // ---- packA: block = (t2, kc). Stage only even rows (0,2,..,12) = 98 floats/ch.
        const int t2 = bid / 24, kc = bid % 24;
        for (int f = tid; f < 64 * 98; f += 256) {
            int c = f / 98, rp = f % 98;                 // rp = row7*14 + col
            int row = (rp / 14) * 2, col = rp % 14;
            smA[c * 99 + rp] = y[(size_t)(kc * 64 + c) * 3136 + t2 * 196 + row * 14 + col];
        }
        __syncthreads();
        for (int item = tid; item < 64 * 49; item += 256) {
            int c = item & 63, ij = item >> 6;
            int i = ij / 7, j = ij % 7;
            Ap[(size_t)(t2 * 49 + ij) * KD + kc * 64 + c] =
                f2bf(smA[c * 99 + i * 14 + 2 * j]);
        }
    } else {
        // ---- packB: conv_w fp32 [o][c] -> bf16 [ND][KD], fully coalesced
        size_t base = (size_t)(bid - 384) * 12288;
#pragma unroll
        for (int v = 0; v < 12; ++v) {
            size_t e = base + v * 1024 + tid * 4;
            float4 w4 = *(const float4*)(conv_w + e);
            ushort4 o;
            o.x = f2bf(w4.x); o.y = f2bf(w4.y); o.z = f2bf(w4.z); o.w = f2bf(w4.w);
            *(ushort4*)(Bp + e) = o;
        }
        // no zerofill: gemm discards rows >= 784 (poison there is benign)
    }
}

// =============== streaming fused gemm: block = (64-ch chunk, t), 128 threads (2 waves).
// K-loop is PURE global->register->MFMA: no LDS, no barriers, no DMA staging. Each wave
// owns a 32x64 tile (acc[2][4]); per K-tile (BK=64): 12 dwordx4 frag loads + 16 MFMA.
// X/Y register sets, 2x-unrolled (all indices compile-time -> no scratch). Fragment
// addresses = the exact logical chunk layout verified in r0-r8 (row = base+l15,
// k = kt + (ko*4+quad)*8). A/B reuse is served by L1 (waves share B) and L2/L3
// (blocks share panels) - offloads the formerly-saturated LDS pipe onto idle memory pipes.
// Epilogue (unchanged from r8): stage x_t frame tile in LDS, bilinear ROI (zero-weight
// masking), BN + exact GELU + *mr, scatter-ADD, coalesced writeout.
__global__ __launch_bounds__(128, 2) void gemm_k(const unsigned short* __restrict__ Ap,
                                                 const unsigned short* __restrict__ Bp,
                                                 const float* __restrict__ cb,
                                                 const float* __restrict__ gm,
                                                 const float* __restrict__ bt,
                                                 const float* __restrict__ rm,
                                                 const float* __restrict__ rv,
                                                 const float* __restrict__ x_t,
                                                 const float* __restrict__ rois,
                                                 float* __restrict__ out) {
    __shared__ __align__(16) float sm[64 * 196];   // 50,176 B frame tile (64 ch x 196 px)
    __shared__ float wx0s[14], wx1s[14], wy0s[14], wy1s[14];
    __shared__ int x0s[14], x1s[14], y0s[14], y1s[14];

    const int tid = threadIdx.x;
    const int n0 = blockIdx.x * 64;
    const int t = blockIdx.y;
    const int aRow0 = t * 49;
    const int wv = tid >> 6;          // 0..1 (M-split: rows wv*32..wv*32+31)
    const int lane = tid & 63;
    const int l15 = lane & 15, quad = lane >> 4;

    // ROI geometry params; validity folded into weights (invalid -> 0, exact).
    // Ordered vs phase-2 reads by the post-K-loop __syncthreads().
    if (tid < 14) {
        float b0 = rois[t * 4 + 0] * 0.0625f, b1 = rois[t * 4 + 1] * 0.0625f;
        float b2 = rois[t * 4 + 2] * 0.0625f, b3 = rois[t * 4 + 3] * 0.0625f;
        float rw = fmaxf(b2 - b0, 1.0f), rh = fmaxf(b3 - b1, 1.0f);
        float bw = rw * (1.0f / 7.0f), bh = rh * (1.0f / 7.0f);
        int p = tid;
        float pos = (float)(p >> 1) + 0.25f + 0.5f * (float)(p & 1);
        float xs = b0 + pos * bw;
        float ysv = b1 + pos * bh;
        bool vx = (xs >= -1.0f && xs <= 14.0f);
        bool vy = (ysv >= -1.0f && ysv <= 14.0f);
        float xc = fminf(fmaxf(xs, 0.0f), 13.0f);
        float yc = fminf(fmaxf(ysv, 0.0f), 13.0f);
        int x0 = (int)floorf(xc), y0 = (int)floorf(yc);
        x0s[p] = x0; y0s[p] = y0;
        x1s[p] = min(x0 + 1, 13); y1s[p] = min(y0 + 1, 13);
        float lx = xc - (float)x0, ly = yc - (float)y0;
        wx0s[p] = vx ? (1.0f - lx) : 0.0f; wx1s[p] = vx ? lx : 0.0f;
        wy0s[p] = vy ? (1.0f - ly) : 0.0f; wy1s[p] = vy ? ly : 0.0f;
    }

    // fragment pointers (short8 units). Row = panel + l15; ko/quad k-offsets folded below.
    const short8* pa0 = (const short8*)(Ap + (size_t)(aRow0 + wv * 32 + l15) * KD) + quad;
    const short8* pa1 = pa0 + 2 * KD;                  // +16 rows
    const short8* pb0 = (const short8*)(Bp + (size_t)(n0 + l15) * KD) + quad;
    const short8* pb1 = pb0 + 2 * KD;                  // +16 cols
    const short8* pb2 = pb0 + 4 * KD;
    const short8* pb3 = pb0 + 6 * KD;

    floatx4 acc[2][4] = {};   // [mi][ni], all indices compile-time below

    short8 xa00, xa01, xa10, xa11, xb00, xb01, xb10, xb11, xb20, xb21, xb30, xb31;
    short8 ya00, ya01, ya10, ya11, yb00, yb01, yb10, yb11, yb20, yb21, yb30, yb31;

#define LDSET(P, T) { const int kk = (T) * 8;                              \
        P##a00 = pa0[kk]; P##a01 = pa0[kk + 4];                            \
        P##a10 = pa1[kk]; P##a11 = pa1[kk + 4];                            \
        P##b00 = pb0[kk]; P##b01 = pb0[kk + 4];                            \
        P##b10 = pb1[kk]; P##b11 = pb1[kk + 4];                            \
        P##b20 = pb2[kk]; P##b21 = pb2[kk + 4];                            \
        P##b30 = pb3[kk]; P##b31 = pb3[kk + 4]; }

#define FMASET(P)                                                          \
        acc[0][0] = MF(P##a00, P##b00, acc[0][0]);                         \
        acc[0][1] = MF(P##a00, P##b10, acc[0][1]);                         \
        acc[0][2] = MF(P##a00, P##b20, acc[0][2]);                         \
        acc[0][3] = MF(P##a00, P##b30, acc[0][3]);                         \
        acc[1][0] = MF(P##a10, P##b00, acc[1][0]);                         \
        acc[1][1] = MF(P##a10, P##b10, acc[1][1]);                         \
        acc[1][2] = MF(P##a10, P##b20, acc[1][2]);                         \
        acc[1][3] = MF(P##a10, P##b30, acc[1][3]);                         \
        acc[0][0] = MF(P##a01, P##b01, acc[0][0]);                         \
        acc[0][1] = MF(P##a01, P##b11, acc[0][1]);                         \
        acc[0][2] = MF(P##a01, P##b21, acc[0][2]);                         \
        acc[0][3] = MF(P##a01, P##b31, acc[0][3]);                         \
        acc[1][0] = MF(P##a11, P##b01, acc[1][0]);                         \
        acc[1][1] = MF(P##a11, P##b11, acc[1][1]);                         \
        acc[1][2] = MF(P##a11, P##b21, acc[1][2]);                         \
        acc[1][3] = MF(P##a11, P##b31, acc[1][3]);

    // K-loop: 24 tiles, 2x software pipeline via X/Y sets (depth-1 tile prefetch + wave TLP)
    LDSET(x, 0)
    for (int it2 = 0; it2 < 12; ++it2) {
        LDSET(y, 2 * it2 + 1)
        FMASET(x)
        if (it2 < 11) { LDSET(x, 2 * it2 + 2) }
        FMASET(y)
    }

    // ---- epilogue phase 1: stage x_t frame tile (64ch x 196px) via float4
    for (int i4 = tid; i4 < 64 * 49; i4 += 128) {
        int c = i4 / 49, p4 = i4 % 49;
        float4 xv = *(const float4*)(x_t + (size_t)(n0 + c) * 3136 + t * 196 + p4 * 4);
        *(float4*)(&sm[c * 196 + p4 * 4]) = xv;
    }
    __syncthreads();

    // ---- phase 2: per acc element compute mr (bilinear, zero-weight masking), BN+GELU, *mr
#pragma unroll
    for (int ni = 0; ni < 4; ++ni) {
        const int cl = ni * 16 + l15;            // 0..63
        const int n = n0 + cl;
        const float scale = gm[n] / sqrtf(rv[n] + 1e-6f);
        const float shift = (cb[n] - rm[n]) * scale + bt[n];
        const float* base = &sm[cl * 196];
#pragma unroll
        for (int mi = 0; mi < 2; ++mi) {
#pragma unroll
            for (int r = 0; r < 4; ++r) {
                const int m = wv * 32 + mi * 16 + quad * 4 + r;
                if (m < 49) {
                    const int i = m / 7, j = m % 7;
                    float sum = 0.0f;
#pragma unroll
                    for (int s = 0; s < 2; ++s) {
                        int pp = 2 * i + s;
#pragma unroll
                        for (int u = 0; u < 2; ++u) {
                            int q = 2 * j + u;
                            float v00 = base[y0s[pp] * 14 + x0s[q]];
                            float v01 = base[y0s[pp] * 14 + x1s[q]];
                            float v10 = base[y1s[pp] * 14 + x0s[q]];
                            float v11 = base[y1s[pp] * 14 + x1s[q]];
                            sum += wy0s[pp] * (wx0s[q] * v00 + wx1s[q] * v01) +
                                   wy1s[pp] * (wx0s[q] * v10 + wx1s[q] * v11);
                        }
                    }
                    const float mrv = 0.25f * sum;
                    const float v = acc[mi][ni][r] * scale + shift;
                    const float g = 0.5f * v * (1.0f + erff(v * 0.70710678118654752f));
                    acc[mi][ni][r] = g * mrv;
                }
            }
        }
    }
    __syncthreads();   // all bilinear reads of sm done before scatter-adds modify it

    // ---- phase 3: scatter-ADD w into the staged tile (distinct (pixel,channel) per element)
    float b0 = rois[t * 4 + 0] * 0.0625f, b1 = rois[t * 4 + 1] * 0.0625f;
    float b2 = rois[t * 4 + 2] * 0.0625f, b3 = rois[t * 4 + 3] * 0.0625f;
    int sxi = (int)floorf(b0), syi = (int)floorf(b1);
    int exi = (int)ceilf(b2), eyi = (int)ceilf(b3);
    int ml = (sxi + 7 < 14) ? sxi : exi - 7;
    int mt = (syi + 7 < 14) ? syi : eyi - 7;
    ml = min(max(ml, 0), 7);
    mt = min(max(mt, 0), 7);

#pragma unroll
    for (int ni = 0; ni < 4; ++ni) {
        const int cl = ni * 16 + l15;
#pragma unroll
        for (int mi = 0; mi < 2; ++mi) {
#pragma unroll
            for (int r = 0; r < 4; ++r) {
                const int m = wv * 32 + mi * 16 + quad * 4 + r;
                if (m < 49) {
                    const int i = m / 7, j = m % 7;
                    sm[cl * 196 + (mt + i) * 14 + (ml + j)] += acc[mi][ni][r];
                }
            }
        }
    }
    __syncthreads();

    // ---- phase 4: write tile out = x_t + scatter(W): LDS float4 -> coalesced global store
    for (int i4 = tid; i4 < 64 * 49; i4 += 128) {
        int c = i4 / 49, p4 = i4 % 49;
        float4 xv = *(const float4*)(&sm[c * 196 + p4 * 4]);
        size_t e0 = (size_t)(n0 + c) * 3136 + t * 196 + p4 * 4;
        *(float4*)(out + e0) = xv;
    }
}

extern "C" void kernel_launch(void* const* d_in, const int* in_sizes, int n_in,
                              void* d_out, int out_size, void* d_ws, size_t ws_size,
                              hipStream_t stream) {
    const float* y = (const float*)d_in[0];
    const float* x_t = (const float*)d_in[1];
    const float* rois = (const float*)d_in[2];
    const float* conv_w = (const float*)d_in[3];
    const float* cb = (const float*)d_in[4];
    const float* gm = (const float*)d_in[5];
    const float* bt = (const float*)d_in[6];
    const float* rm = (const float*)d_in[7];
    const float* rv = (const float*)d_in[8];
    float* out = (float*)d_out;

    char* ws = (char*)d_ws;
    unsigned short* Ap = (unsigned short*)ws;                 // 832*1536*2 B (rows >= 784 poison: read for t=15 tile tail, outputs discarded)
    unsigned short* Bp = (unsigned short*)(ws + 2555904);     // 3072*1536*2 = 9,437,184 B

    prep_k<<<768, 256, 0, stream>>>(y, conv_w, Ap, Bp);
    gemm_k<<<dim3(ND / 64, TT), 128, 0, stream>>>(Ap, Bp, cb, gm, bt, rm, rv, x_t, rois, out);
}